// Round 12
// baseline (2522.091 us; speedup 1.0000x reference)
//
#include <hip/hip_runtime.h>

#define CCH 768
#define LL  197
#define L199 199
#define KC  2304          // K per tap (T0 dropped)
#define KTOT 6912         // 3 taps fused along K
#define MK2 1769472       // 768*2304
#define NVALID 12736      // 64*199 GEMM row space
#define NROW 12608        // 64*197 valid rows (compacted)

typedef __bf16 bf16x8 __attribute__((ext_vector_type(8)));
typedef float f32x2 __attribute__((ext_vector_type(2)));
typedef float f32x4 __attribute__((ext_vector_type(4)));
typedef float f32x16 __attribute__((ext_vector_type(16)));

__device__ __forceinline__ unsigned short f2bf(float f) {
  unsigned int u = __float_as_uint(f);
  u += 0x7FFFu + ((u >> 16) & 1u);           // RNE
  return (unsigned short)(u >> 16);
}
__device__ __forceinline__ float bf2f(unsigned short h) {
  return __uint_as_float(((unsigned int)h) << 16);
}

// ---- fused weight pack + d0 bias (R10-proven)
__global__ void pack_bias(const float* __restrict__ Wq, const float* __restrict__ Wk,
                          const float* __restrict__ Wv, unsigned short* __restrict__ Apack,
                          float* __restrict__ bias3, size_t pack1_halves) {
  __shared__ float wrow[9216];               // 3072*3 floats = 36 KB
  __shared__ float red0[256], red1[256], red2[256];
  const int bid = blockIdx.x;                // 2304 = 3*768
  const int proj = bid / 768, m = bid % 768;
  const int t = threadIdx.x;
  const float* W = proj == 0 ? Wq : (proj == 1 ? Wk : Wv);
  const float* src = W + (size_t)m * 9216;
#pragma unroll
  for (int s = 0; s < 36; ++s) wrow[t + 256 * s] = src[t + 256 * s];
  __syncthreads();
  float s0 = 0.f, s1 = 0.f, s2 = 0.f;
  for (int c = t; c < 768; c += 256) {
    s0 += wrow[12 * c];
    s1 += wrow[12 * c + 1];
    s2 += wrow[12 * c + 2];
  }
  red0[t] = s0; red1[t] = s1; red2[t] = s2;
  unsigned short* Ahi = Apack + (size_t)proj * pack1_halves;
  unsigned short* Alo = Ahi + (size_t)768 * KTOT;
#pragma unroll
  for (int s = 0; s < 9; ++s) {
    int u = t + 256 * s;                     // 0..2303
    int c = u / 3, dm1 = u % 3;
    int ci = c * 4 + dm1 + 1;
#pragma unroll
    for (int tap = 0; tap < 3; ++tap) {
      float f = wrow[ci * 3 + tap];
      unsigned short hi = f2bf(f);
      unsigned short lo = f2bf(f - bf2f(hi));
      size_t idx = (size_t)m * KTOT + tap * KC + u;
      Ahi[idx] = hi;
      Alo[idx] = lo;
    }
  }
  __syncthreads();
  for (int off = 128; off; off >>= 1) {
    if (t < off) {
      red0[t] += red0[t + off];
      red1[t] += red1[t + off];
      red2[t] += red2[t + off];
    }
    __syncthreads();
  }
  if (t == 0) {
    bias3[proj * 2304 + m] = red0[0];
    bias3[proj * 2304 + 768 + m] = red1[0];
    bias3[proj * 2304 + 1536 + m] = red2[0];
  }
}

// ---- z: T_{1..3}(tanh(x)) -> Z (12740 rows, 2304) hi/lo bf16; row = b*199 + 1 + l
__global__ void z_kernel(const float* __restrict__ x, unsigned short* __restrict__ Zhi,
                         unsigned short* __restrict__ Zlo) {
  __shared__ float zs[3][32][33];
  int c0 = blockIdx.x * 32, l0 = blockIdx.y * 32, b = blockIdx.z;
  int t = threadIdx.x;
#pragma unroll
  for (int s = 0; s < 4; ++s) {
    int u = t + 256 * s;
    int rc = u >> 5, cl = u & 31;            // rc: channel, cl: position
    float v = 0.f;
    if (l0 + cl < LL) v = x[((size_t)b * CCH + c0 + rc) * LL + l0 + cl];
    float t1 = tanhf(v);
    zs[0][rc][cl] = t1;
    zs[1][rc][cl] = 2.f * t1 * t1 - 1.f;
    zs[2][rc][cl] = t1 * (4.f * t1 * t1 - 3.f);
  }
  __syncthreads();
#pragma unroll
  for (int s = 0; s < 12; ++s) {
    int w = t + 256 * s;                     // 32 rows x 96 cols
    int rl = w / 96, cc = w % 96;
    if (l0 + rl < LL) {
      int cl2 = cc / 3, dm1 = cc % 3;
      float v = zs[dm1][cl2][rl];
      unsigned short hi = f2bf(v);
      unsigned short lo = f2bf(v - bf2f(hi));
      size_t row = (size_t)b * L199 + 1 + l0 + rl;
      Zhi[row * KC + c0 * 3 + cc] = hi;
      Zlo[row * KC + c0 * 3 + cc] = lo;
    }
  }
}

__global__ void zero_zpad(unsigned short* __restrict__ Zhi, unsigned short* __restrict__ Zlo) {
  int u = blockIdx.x * 256 + threadIdx.x;    // 132 rows * 2304
  if (u >= 132 * KC) return;
  int rowi = u / KC, c = u % KC;
  size_t r = (rowi < 128) ? ((size_t)(rowi >> 1) * L199 + (size_t)(rowi & 1) * 198)
                          : ((size_t)NVALID + rowi - 128);   // 12736..12739
  Zhi[r * KC + c] = 0;
  Zlo[r * KC + c] = 0;
}

#define GLL(SRC, DST) \
  __builtin_amdgcn_global_load_lds( \
      (const __attribute__((address_space(1))) void*)(SRC), \
      (__attribute__((address_space(3))) void*)(DST), 16, 0, 0)

// ---- merged GEMM v2: 256x128 tile, BK=16, 512 threads (8 waves, 2M x 4N,
// per-wave 128x32), double-buffered 48 KB LDS -> TWO blocks/CU co-resident
// (the m114 overlap mechanism; R6 structure was LDS/VGPR-capped at 1 block).
// acc = 4 x f32x16 = 64 regs; __launch_bounds__(512,4) targets <=128/wave.
// Schedule = R6-proven phase discipline at identical per-K rates:
//   ph0: read B(2)+A quads 0,1(4) from buf[i&1]; stage slab i+1 units {u0,u1}
//        -> other buf; barrier+lgkm0; 12 MFMA; barrier.
//   ph1: read A quads 2,3(4); stage slab i+2 unit {u2} -> SAME buf (u2 chosen
//        from units consumed in ph0 and not read in ph1 -- safe overwrite);
//        barrier+lgkm0; 12 MFMA; end-of-step COUNTED vmcnt(1)+barrier.
// LDS unit = 32 rows x 16 halves, frag-linear (lane l's 8 halves at l*8) --
// GLL per-lane global src = (row base + (lane&31))*rs + (lane>>5)*8, dest
// linear => conflict-free b128 frag reads. 24 units/slab, 3 per wave.
// Grid 900 = 100 n-tiles x 3 proj x 3 m-tiles, bijective XCD chunking.
__global__ __launch_bounds__(512, 4) void conv_gemm3(const unsigned short* __restrict__ Apack,
                                                     const unsigned short* __restrict__ Zhi,
                                                     const unsigned short* __restrict__ Zlo,
                                                     const float* __restrict__ bias3,
                                                     float* __restrict__ Oqk,
                                                     float* __restrict__ Ov) {
  __shared__ unsigned short lds[2 * 12288];  // [buf][Ah 4096|Al 4096|Bh 2048|Bl 2048]
  const int bid = blockIdx.x;                // 900
  const int xcd = bid & 7, loc = bid >> 3;   // xcd 0..3 own 113 wgs; 4..7 own 112
  const int wg = (xcd < 4) ? (xcd * 113 + loc) : (452 + (xcd - 4) * 112 + loc);
  const int n_t = wg / 9, rem = wg % 9;
  const int proj = rem / 3, m_t = rem % 3;
  const int m_blk = m_t * 256, n_blk = n_t * 128;
  const unsigned short* Ahi = Apack + (size_t)proj * 2 * 768 * KTOT;
  const unsigned short* Alo = Ahi + (size_t)768 * KTOT;
  const float* bias3p = bias3 + proj * 2304;
  float* Op = (proj == 2) ? Ov : Oqk + (size_t)proj * NROW * CCH;

  const int t = threadIdx.x;
  const int wave = t >> 6, lane = t & 63;
  const int wm = (wave >> 2) * 128;          // 2 M-groups of 128
  const int wn = (wave & 3) * 32;            // 4 N-columns of 32
  const int g = wave >> 2;
  const int fb = lane * 8;                   // frag-linear lane term (halves)
  const int aq = g * 2048;                   // A quad base: unit (g*4+Q)*512
  const int bu = (wave & 3) * 512;           // B unit base
  f32x16 acc[4] = {};

  // unit ownership: wave stages 3 units/slab. uu[0] (ph0) = the "unsafe" unit
  // (read during ph1: Ah/Al quads 2,3); uu[1] (ph0), uu[2] (ph1) = safe units.
  int uu[3];
  uu[0] = 4 * (wave >> 1) + 2 + (wave & 1);                  // {2,3,6,7,10,11,14,15}
  uu[1] = (wave < 4) ? 4 * wave : 2 * wave + 8;              // {0,4,8,12,16,18,20,22}
  uu[2] = (wave < 4) ? 4 * wave + 1 : 2 * wave + 9;          // {1,5,9,13,17,19,21,23}
  const unsigned short* srcs[3];
  int doff[3];
#pragma unroll
  for (int j = 0; j < 3; ++j) {
    int u = uu[j];
    doff[j] = u * 512;
    const unsigned short* gp;
    int r, rs;
    if (u < 16) {                            // A: Ah units 0-7, Al units 8-15
      int tile = u >> 3, p = u & 7;
      r = m_blk + p * 32 + (lane & 31);
      gp = tile ? Alo : Ahi;
      rs = KTOT;
    } else {                                 // B: Bh units 16-19, Bl 20-23
      int tile = (u - 16) >> 2, p = u & 3;
      r = n_blk + p * 32 + (lane & 31);
      if (r > 12737) r = 12737;              // clamp into zeroed tail
      gp = tile ? Zlo : Zhi;
      rs = KC;
    }
    srcs[j] = gp + (size_t)r * rs + (lane >> 5) * 8;
  }

  const int NIT = KTOT / 16;                 // 432
  // prologue: slab0 (3 units) -> buf0; slab1 ph1-unit -> buf1
  GLL(srcs[0], lds + doff[0]);
  GLL(srcs[1], lds + doff[1]);
  GLL(srcs[2], lds + doff[2]);
  GLL(srcs[2] + 16, lds + 12288 + doff[2]);
  asm volatile("s_waitcnt vmcnt(1)\n\ts_barrier" ::: "memory");
  __builtin_amdgcn_sched_barrier(0);

  for (int i = 0; i < NIT; ++i) {
    const unsigned short* lb = lds + ((i & 1) ? 12288 : 0);
    unsigned short* oth = lds + ((i & 1) ? 0 : 12288);
    unsigned short* cur = lds + ((i & 1) ? 12288 : 0);

    // ---------- ph0: B + A quads 0,1; stage slab i+1 units uu[0],uu[1] ----------
    bf16x8 bh = *(const bf16x8*)(lb + 8192 + bu + fb);
    bf16x8 bl = *(const bf16x8*)(lb + 10240 + bu + fb);
    bf16x8 a0h = *(const bf16x8*)(lb + aq + fb);
    bf16x8 a0l = *(const bf16x8*)(lb + 4096 + aq + fb);
    bf16x8 a1h = *(const bf16x8*)(lb + aq + 512 + fb);
    bf16x8 a1l = *(const bf16x8*)(lb + 4096 + aq + 512 + fb);
    if (i + 1 < NIT) {
      const int ko = 16 * (i + 1);
      GLL(srcs[0] + ko, oth + doff[0]);
      GLL(srcs[1] + ko, oth + doff[1]);
    }
    asm volatile("s_barrier\n\ts_waitcnt lgkmcnt(0)" ::: "memory");
    __builtin_amdgcn_sched_barrier(0);
    __builtin_amdgcn_s_setprio(1);
    acc[0] = __builtin_amdgcn_mfma_f32_32x32x16_bf16(a0h, bh, acc[0], 0, 0, 0);
    acc[0] = __builtin_amdgcn_mfma_f32_32x32x16_bf16(a0h, bl, acc[0], 0, 0, 0);
    acc[0] = __builtin_amdgcn_mfma_f32_32x32x16_bf16(a0l, bh, acc[0], 0, 0, 0);
    acc[1] = __builtin_amdgcn_mfma_f32_32x32x16_bf16(a1h, bh, acc[1], 0, 0, 0);
    acc[1] = __builtin_amdgcn_mfma_f32_32x32x16_bf16(a1h, bl, acc[1], 0, 0, 0);
    acc[1] = __builtin_amdgcn_mfma_f32_32x32x16_bf16(a1l, bh, acc[1], 0, 0, 0);
    __builtin_amdgcn_s_setprio(0);
    asm volatile("s_barrier" ::: "memory");
    __builtin_amdgcn_sched_barrier(0);

    // ---------- ph1: A quads 2,3; stage slab i+2 unit uu[2] (safe) ----------
    bf16x8 a2h = *(const bf16x8*)(lb + aq + 1024 + fb);
    bf16x8 a2l = *(const bf16x8*)(lb + 4096 + aq + 1024 + fb);
    bf16x8 a3h = *(const bf16x8*)(lb + aq + 1536 + fb);
    bf16x8 a3l = *(const bf16x8*)(lb + 4096 + aq + 1536 + fb);
    if (i + 2 < NIT) {
      GLL(srcs[2] + 16 * (i + 2), cur + doff[2]);
    }
    asm volatile("s_barrier\n\ts_waitcnt lgkmcnt(0)" ::: "memory");
    __builtin_amdgcn_sched_barrier(0);
    __builtin_amdgcn_s_setprio(1);
    acc[2] = __builtin_amdgcn_mfma_f32_32x32x16_bf16(a2h, bh, acc[2], 0, 0, 0);
    acc[2] = __builtin_amdgcn_mfma_f32_32x32x16_bf16(a2h, bl, acc[2], 0, 0, 0);
    acc[2] = __builtin_amdgcn_mfma_f32_32x32x16_bf16(a2l, bh, acc[2], 0, 0, 0);
    acc[3] = __builtin_amdgcn_mfma_f32_32x32x16_bf16(a3h, bh, acc[3], 0, 0, 0);
    acc[3] = __builtin_amdgcn_mfma_f32_32x32x16_bf16(a3h, bl, acc[3], 0, 0, 0);
    acc[3] = __builtin_amdgcn_mfma_f32_32x32x16_bf16(a3l, bh, acc[3], 0, 0, 0);
    __builtin_amdgcn_s_setprio(0);
    // end-of-step: slab i+1 complete (oldest 3 of 4 in flight); counted wait
    if (i < NIT - 2) {
      asm volatile("s_waitcnt vmcnt(1)\n\ts_barrier" ::: "memory");
    } else if (i == NIT - 2) {
      asm volatile("s_waitcnt vmcnt(0)\n\ts_barrier" ::: "memory");
    }
    __builtin_amdgcn_sched_barrier(0);
  }

  // epilogue: C/D layout col=lane&31, row=(reg&3)+8*(reg>>2)+4*(lane>>5)
  int n = n_blk + wn + (lane & 31);
  int nb_ = n / L199, nl = n - nb_ * L199;
  bool val = (n < NVALID) && (nl < LL);
  int row = nb_ * LL + nl;
  bool v0 = (nl == 0), v2 = (nl == 196);
#pragma unroll
  for (int mb = 0; mb < 4; ++mb) {
#pragma unroll
    for (int q = 0; q < 4; ++q) {
      int m = m_blk + wm + mb * 32 + q * 8 + (lane >> 5) * 4;
      f32x4 b0 = *(const f32x4*)(bias3p + m);
      f32x4 b1 = *(const f32x4*)(bias3p + 768 + m);
      f32x4 b2 = *(const f32x4*)(bias3p + 1536 + m);
      f32x4 bs = b0 + b1 + b2;
      if (val) {
        f32x4 r;
        r[0] = acc[mb][q * 4 + 0];
        r[1] = acc[mb][q * 4 + 1];
        r[2] = acc[mb][q * 4 + 2];
        r[3] = acc[mb][q * 4 + 3];
        r += bs;
        if (v0) r -= b0;
        if (v2) r -= b2;
        *(f32x4*)(Op + (size_t)row * CCH + m) = r;
      }
    }
  }
}

// ---- BN stats over 12608 rows per proj
__global__ void zero_f32(float* __restrict__ p, int n) {
  int u = blockIdx.x * 256 + threadIdx.x;
  if (u < n) p[u] = 0.f;
}

__global__ void bn_stats(const float* __restrict__ Oqk, const float* __restrict__ Ov,
                         float* __restrict__ Ssum, float* __restrict__ Ssq) {
  int proj = blockIdx.z;
  int cb = blockIdx.x * 64;
  int rb = blockIdx.y;                         // 32 chunks of 394 rows
  int t = threadIdx.x;
  int ch = cb + (t & 63);
  int phase = t >> 6;
  const float* Op = (proj == 2) ? Ov : Oqk + (size_t)proj * NROW * CCH;
  float s = 0.f, q = 0.f;
  for (int r = rb * 394 + phase; r < rb * 394 + 394; r += 4) {
    float v = Op[(size_t)r * CCH + ch];
    s += v; q += v * v;
  }
  __shared__ float rs[256], rq[256];
  rs[t] = s; rq[t] = q;
  __syncthreads();
  if (t < 64) {
    float S = rs[t] + rs[t + 64] + rs[t + 128] + rs[t + 192];
    float Q = rq[t] + rq[t + 64] + rq[t + 128] + rq[t + 192];
    atomicAdd(&Ssum[proj * CCH + cb + t], S);
    atomicAdd(&Ssq[proj * CCH + cb + t], Q);
  }
}

__global__ void bn_fin(const float* __restrict__ Ssum, const float* __restrict__ Ssq,
                       const float* __restrict__ sq, const float* __restrict__ bq,
                       const float* __restrict__ sk, const float* __restrict__ bk,
                       const float* __restrict__ sv, const float* __restrict__ bv,
                       float* __restrict__ abn) {
  int u = blockIdx.x * 256 + threadIdx.x;
  if (u >= 3 * CCH) return;
  int proj = u / CCH, ch = u % CCH;
  float mean = Ssum[u] / 12608.f;
  float var = Ssq[u] / 12608.f - mean * mean;
  const float* sc = proj == 0 ? sq : (proj == 1 ? sk : sv);
  const float* bi = proj == 0 ? bq : (proj == 1 ? bk : bv);
  float a = sc[ch] * rsqrtf(var + 1e-5f);
  abn[u * 2] = a;
  abn[u * 2 + 1] = bi[ch] - mean * a;
}

// ---- BN-affine + RoPE -> Qr,Kr (b,l,768)
__global__ void rope_pack(const float* __restrict__ Oqk, const float* __restrict__ abn,
                          const float* __restrict__ freqs, float* __restrict__ Qr,
                          float* __restrict__ Kr) {
  size_t u = (size_t)blockIdx.x * 256 + threadIdx.x;    // 64*197*384
  if (u >= 64ull * LL * 384) return;
  int c2 = (int)(u % 384);
  int l = (int)((u / 384) % LL);
  int b = (int)(u / (384ull * LL));
  size_t rowO = ((size_t)b * LL + l) * CCH + 2 * c2;
  const float* Ok = Oqk + (size_t)NROW * CCH;
  float q0 = Oqk[rowO], q1 = Oqk[rowO + 1];
  float k0 = Ok[rowO], k1 = Ok[rowO + 1];
  float aq0 = abn[(2 * c2) * 2],                bq0 = abn[(2 * c2) * 2 + 1];
  float aq1 = abn[(2 * c2 + 1) * 2],            bq1 = abn[(2 * c2 + 1) * 2 + 1];
  float ak0 = abn[(CCH + 2 * c2) * 2],          bk0 = abn[(CCH + 2 * c2) * 2 + 1];
  float ak1 = abn[(CCH + 2 * c2 + 1) * 2],      bk1 = abn[(CCH + 2 * c2 + 1) * 2 + 1];
  q0 = q0 * aq0 + bq0; q1 = q1 * aq1 + bq1;
  k0 = k0 * ak0 + bk0; k1 = k1 * ak1 + bk1;
  if (l > 0) {
    int tt = l - 1;
    float tx = (float)(tt % 14), ty = (float)(tt / 14);
    float ang = tx * freqs[c2] + ty * freqs[384 + c2];
    float sn, cs;
    sincosf(ang, &sn, &cs);
    float r0 = q0 * cs - q1 * sn, r1 = q0 * sn + q1 * cs;
    q0 = r0; q1 = r1;
    r0 = k0 * cs - k1 * sn; r1 = k0 * sn + k1 * cs;
    k0 = r0; k1 = r1;
  }
  size_t rowT = ((size_t)b * LL + l) * CCH + 2 * c2;
  Qr[rowT] = q0; Qr[rowT + 1] = q1;
  Kr[rowT] = k0; Kr[rowT + 1] = k1;
}

// ---- energy = Qr Kr^T, 64x64 tile, 16x16 threads, 4x4 register block.
__global__ void energy_k(const float* __restrict__ Qr, const float* __restrict__ Kr,
                         float* __restrict__ E) {
  __shared__ float Qs[64][33], Ks[64][33];
  int i0 = blockIdx.x * 64, j0 = blockIdx.y * 64, b = blockIdx.z;
  int t = threadIdx.x, tj = t & 15, ti = t >> 4;
  float acc[4][4] = {};
  const float* Qb = Qr + (size_t)b * LL * CCH;
  const float* Kb = Kr + (size_t)b * LL * CCH;
  for (int k0 = 0; k0 < CCH; k0 += 32) {
    __syncthreads();
#pragma unroll
    for (int s = 0; s < 8; ++s) {
      int u = t + 256 * s, r = u >> 5, cc = u & 31;
      Qs[r][cc] = (i0 + r < LL) ? Qb[(size_t)(i0 + r) * CCH + k0 + cc] : 0.f;
      Ks[r][cc] = (j0 + r < LL) ? Kb[(size_t)(j0 + r) * CCH + k0 + cc] : 0.f;
    }
    __syncthreads();
#pragma unroll
    for (int kk = 0; kk < 32; ++kk) {
      float qv[4], kv[4];
#pragma unroll
      for (int q = 0; q < 4; ++q) qv[q] = Qs[ti * 4 + q][kk];
#pragma unroll
      for (int j = 0; j < 4; ++j) kv[j] = Ks[tj * 4 + j][kk];
#pragma unroll
      for (int q = 0; q < 4; ++q)
#pragma unroll
        for (int j = 0; j < 4; ++j) acc[q][j] += qv[q] * kv[j];
    }
  }
#pragma unroll
  for (int q = 0; q < 4; ++q) {
    int i = i0 + ti * 4 + q;
    if (i >= LL) continue;
#pragma unroll
    for (int j = 0; j < 4; ++j) {
      int jj = j0 + tj * 4 + j;
      if (jj < LL) E[((size_t)b * LL + i) * LL + jj] = acc[q][j];
    }
  }
}

__global__ void softmax_k(float* __restrict__ E) {
  int row = blockIdx.x;                // 64*197
  int lane = threadIdx.x;              // 64
  float* Er = E + (size_t)row * LL;
  float v[4];
  float m = -3.4e38f;
#pragma unroll
  for (int q = 0; q < 4; ++q) {
    int j = lane + 64 * q;
    v[q] = (j < LL) ? Er[j] : -3.4e38f;
    m = fmaxf(m, v[q]);
  }
  for (int off = 32; off; off >>= 1) m = fmaxf(m, __shfl_down(m, off));
  m = __shfl(m, 0);
  float s = 0.f;
#pragma unroll
  for (int q = 0; q < 4; ++q) {
    int j = lane + 64 * q;
    v[q] = (j < LL) ? expf(v[q] - m) : 0.f;
    s += v[q];
  }
  for (int off = 32; off; off >>= 1) s += __shfl_down(s, off);
  s = __shfl(s, 0);
  float inv = 1.f / s;
#pragma unroll
  for (int q = 0; q < 4; ++q) {
    int j = lane + 64 * q;
    if (j < LL) Er[j] = v[q] * inv;
  }
}

// ---- fused AV + transpose: Y(b, c, i) = gamma*x + (a*[att@V] + b)^T.
__global__ void av_y(const float* __restrict__ att, const float* __restrict__ Ov,
                     const float* __restrict__ abn, const float* __restrict__ x,
                     const float* __restrict__ gamma, float* __restrict__ Y) {
  __shared__ float As[32][33];
  __shared__ float Vs[32][128];
  __shared__ float Ts[32][129];
  int i0 = blockIdx.x * 32, c0 = blockIdx.y * 128, b = blockIdx.z;
  int t = threadIdx.x, tc = t & 63, tq = t >> 6;
  const float* attb = att + (size_t)b * LL * LL;
  float acc[8][2] = {};
  for (int j0 = 0; j0 < LL; j0 += 32) {
    __syncthreads();
#pragma unroll
    for (int s = 0; s < 4; ++s) {
      int u = t + 256 * s, r = u >> 5, cc = u & 31;
      As[r][cc] = (i0 + r < LL && j0 + cc < LL) ? attb[(size_t)(i0 + r) * LL + j0 + cc] : 0.f;
    }
#pragma unroll
    for (int s = 0; s < 16; ++s) {
      int u = t + 256 * s, r = u >> 7, cc = u & 127;
      Vs[r][cc] = (j0 + r < LL) ? Ov[((size_t)b * LL + j0 + r) * CCH + c0 + cc] : 0.f;
    }
    __syncthreads();
#pragma unroll
    for (int jj = 0; jj < 32; ++jj) {
      f32x2 vv = *(const f32x2*)&Vs[jj][2 * tc];
#pragma unroll
      for (int q = 0; q < 8; ++q) {
        float a = As[tq * 8 + q][jj];
        acc[q][0] += a * vv[0];
        acc[q][1] += a * vv[1];
      }
    }
  }
  int c = c0 + 2 * tc;
  float a0 = abn[(2 * CCH + c) * 2],     b0 = abn[(2 * CCH + c) * 2 + 1];
  float a1 = abn[(2 * CCH + c + 1) * 2], b1 = abn[(2 * CCH + c + 1) * 2 + 1];
#pragma unroll
  for (int q = 0; q < 8; ++q) {
    int il = tq * 8 + q;
    Ts[il][2 * tc] = a0 * acc[q][0] + b0;
    Ts[il][2 * tc + 1] = a1 * acc[q][1] + b1;
  }
  __syncthreads();
  float g = gamma[0];
#pragma unroll
  for (int s = 0; s < 16; ++s) {
    int u = t + 256 * s, cc = u >> 5, il = u & 31;   // cc: 0..127, il: 0..31
    if (i0 + il < LL) {
      size_t idx = ((size_t)b * CCH + c0 + cc) * LL + i0 + il;
      Y[idx] = g * x[idx] + Ts[il][cc];
    }
  }
}

// ---- fused BN(Y) + apply
__global__ void bn_y_final(const float* __restrict__ Y, const float* __restrict__ ns,
                           const float* __restrict__ nb, float* __restrict__ out) {
  __shared__ float ych[12608];
  __shared__ float rs[256], rq[256];
  int c = blockIdx.x;
  int t = threadIdx.x;
  float s = 0.f, q = 0.f;
  for (int u = t; u < 12608; u += 256) {
    int b = u / LL, l = u - b * LL;
    float v = Y[((size_t)b * CCH + c) * LL + l];
    ych[u] = v;
    s += v; q += v * v;
  }
  rs[t] = s; rq[t] = q;
  __syncthreads();
  for (int off = 128; off; off >>= 1) {
    if (t < off) { rs[t] += rs[t + off]; rq[t] += rq[t + off]; }
    __syncthreads();
  }
  float mean = rs[0] / 12608.f, var = rq[0] / 12608.f - mean * mean;
  float a = ns[c] * rsqrtf(var + 1e-5f);
  float bb = nb[c] - mean * a;
  for (int u = t; u < 12608; u += 256) {
    int b = u / LL, l = u - b * LL;
    out[((size_t)b * CCH + c) * LL + l] = a * ych[u] + bb;
  }
}

extern "C" void kernel_launch(void* const* d_in, const int* in_sizes, int n_in,
                              void* d_out, int out_size, void* d_ws, size_t ws_size,
                              hipStream_t stream) {
  const float* x = (const float*)d_in[0];
  const float* Wq = (const float*)d_in[1];
  const float* Wk = (const float*)d_in[2];
  const float* Wv = (const float*)d_in[3];
  const float* bnq_s = (const float*)d_in[4];
  const float* bnq_b = (const float*)d_in[5];
  const float* bnk_s = (const float*)d_in[6];
  const float* bnk_b = (const float*)d_in[7];
  const float* bnv_s = (const float*)d_in[8];
  const float* bnv_b = (const float*)d_in[9];
  const float* gamma = (const float*)d_in[10];
  const float* freqs = (const float*)d_in[11];
  const float* norm_s = (const float*)d_in[12];
  const float* norm_b = (const float*)d_in[13];
  float* out = (float*)d_out;

  char* ws = (char*)d_ws;
  const size_t QRSZ  = 38731776;                 // 64*197*768*4
  const size_t PACK1 = 21233664;                 // per-proj Ahi+Alo bytes
  const size_t ZSZ   = 58705920;                 // 12740*2304*2

  const size_t OFS_PACK = 0;
  const size_t OFS_Z    = 3 * PACK1;
  const size_t OFS_ZLO  = OFS_Z + ZSZ;
  const size_t OFS_O    = OFS_ZLO + ZSZ;
  const size_t OFS_MISC = OFS_O + 2 * QRSZ;

  unsigned short* Apack = (unsigned short*)(ws + OFS_PACK);
  unsigned short* Zhi = (unsigned short*)(ws + OFS_Z);
  unsigned short* Zlo = (unsigned short*)(ws + OFS_ZLO);
  float* Oqk = (float*)(ws + OFS_O);
  float* bias3 = (float*)(ws + OFS_MISC);              // 27,648 B
  float* Ssum = (float*)(ws + OFS_MISC + 27648);       // 9,216 B
  float* Ssq  = (float*)(ws + OFS_MISC + 36864);       // 9,216 B
  float* abn  = (float*)(ws + OFS_MISC + 46080);       // 18,432 B
  // V lives in d_out until av_y consumes it; bn_y_final overwrites afterwards.
  float* Ov = out;
  // post-GEMM reuse of the Z region (Z dead after the GEMM launch):
  float* Qr = (float*)(ws + OFS_Z);                    // [0, QRSZ)
  float* Kr = (float*)(ws + OFS_Z + QRSZ);             // [QRSZ, 2*QRSZ)
  float* E  = (float*)(ws + OFS_Z + 2 * QRSZ);         // 9,935,104 B
  float* Y  = (float*)(ws + OFS_Z + QRSZ);             // after energy_k (Kr dead)

  zero_zpad<<<dim3((132 * KC + 255) / 256), 256, 0, stream>>>(Zhi, Zlo);
  z_kernel<<<dim3(24, 7, 64), 256, 0, stream>>>(x, Zhi, Zlo);
  pack_bias<<<dim3(2304), 256, 0, stream>>>(Wq, Wk, Wv, Apack, bias3, PACK1 / 2);
  conv_gemm3<<<dim3(900), 512, 0, stream>>>(Apack, Zhi, Zlo, bias3, Oqk, Ov);

  zero_f32<<<dim3(18), 256, 0, stream>>>(Ssum, 4608);   // Ssum+Ssq contiguous
  bn_stats<<<dim3(12, 32, 3), 256, 0, stream>>>(Oqk, Ov, Ssum, Ssq);
  bn_fin<<<dim3(9), 256, 0, stream>>>(Ssum, Ssq, bnq_s, bnq_b, bnk_s, bnk_b, bnv_s, bnv_b, abn);
  rope_pack<<<dim3((unsigned)((64ull * LL * 384 + 255) / 256)), 256, 0, stream>>>(Oqk, abn, freqs, Qr, Kr);
  energy_k<<<dim3(4, 4, 64), 256, 0, stream>>>(Qr, Kr, E);
  softmax_k<<<dim3(64 * LL), 64, 0, stream>>>(E);
  av_y<<<dim3(7, 6, 64), 256, 0, stream>>>(E, Ov, abn, x, gamma, Y);
  bn_y_final<<<dim3(CCH), 256, 0, stream>>>(Y, norm_s, norm_b, out);
}

// Round 13
// 1932.285 us; speedup vs baseline: 1.3052x; 1.3052x over previous
//
#include <hip/hip_runtime.h>

#define CCH 768
#define LL  197
#define L199 199
#define KC  2304          // K per tap (T0 dropped)
#define KTOT 6912         // 3 taps fused along K
#define MK2 1769472       // 768*2304
#define NVALID 12736      // 64*199 GEMM row space
#define NROW 12608        // 64*197 valid rows (compacted)

typedef __bf16 bf16x8 __attribute__((ext_vector_type(8)));
typedef float f32x2 __attribute__((ext_vector_type(2)));
typedef float f32x4 __attribute__((ext_vector_type(4)));
typedef float f32x16 __attribute__((ext_vector_type(16)));

__device__ __forceinline__ unsigned short f2bf(float f) {
  unsigned int u = __float_as_uint(f);
  u += 0x7FFFu + ((u >> 16) & 1u);           // RNE
  return (unsigned short)(u >> 16);
}
__device__ __forceinline__ float bf2f(unsigned short h) {
  return __uint_as_float(((unsigned int)h) << 16);
}

// ---- fused weight pack + d0 bias (R10-proven)
__global__ void pack_bias(const float* __restrict__ Wq, const float* __restrict__ Wk,
                          const float* __restrict__ Wv, unsigned short* __restrict__ Apack,
                          float* __restrict__ bias3, size_t pack1_halves) {
  __shared__ float wrow[9216];               // 3072*3 floats = 36 KB
  __shared__ float red0[256], red1[256], red2[256];
  const int bid = blockIdx.x;                // 2304 = 3*768
  const int proj = bid / 768, m = bid % 768;
  const int t = threadIdx.x;
  const float* W = proj == 0 ? Wq : (proj == 1 ? Wk : Wv);
  const float* src = W + (size_t)m * 9216;
#pragma unroll
  for (int s = 0; s < 36; ++s) wrow[t + 256 * s] = src[t + 256 * s];
  __syncthreads();
  float s0 = 0.f, s1 = 0.f, s2 = 0.f;
  for (int c = t; c < 768; c += 256) {
    s0 += wrow[12 * c];
    s1 += wrow[12 * c + 1];
    s2 += wrow[12 * c + 2];
  }
  red0[t] = s0; red1[t] = s1; red2[t] = s2;
  unsigned short* Ahi = Apack + (size_t)proj * pack1_halves;
  unsigned short* Alo = Ahi + (size_t)768 * KTOT;
#pragma unroll
  for (int s = 0; s < 9; ++s) {
    int u = t + 256 * s;                     // 0..2303
    int c = u / 3, dm1 = u % 3;
    int ci = c * 4 + dm1 + 1;
#pragma unroll
    for (int tap = 0; tap < 3; ++tap) {
      float f = wrow[ci * 3 + tap];
      unsigned short hi = f2bf(f);
      unsigned short lo = f2bf(f - bf2f(hi));
      size_t idx = (size_t)m * KTOT + tap * KC + u;
      Ahi[idx] = hi;
      Alo[idx] = lo;
    }
  }
  __syncthreads();
  for (int off = 128; off; off >>= 1) {
    if (t < off) {
      red0[t] += red0[t + off];
      red1[t] += red1[t + off];
      red2[t] += red2[t + off];
    }
    __syncthreads();
  }
  if (t == 0) {
    bias3[proj * 2304 + m] = red0[0];
    bias3[proj * 2304 + 768 + m] = red1[0];
    bias3[proj * 2304 + 1536 + m] = red2[0];
  }
}

// ---- z: T_{1..3}(tanh(x)) -> Z (12740 rows, 2304) hi/lo bf16; row = b*199 + 1 + l
__global__ void z_kernel(const float* __restrict__ x, unsigned short* __restrict__ Zhi,
                         unsigned short* __restrict__ Zlo) {
  __shared__ float zs[3][32][33];
  int c0 = blockIdx.x * 32, l0 = blockIdx.y * 32, b = blockIdx.z;
  int t = threadIdx.x;
#pragma unroll
  for (int s = 0; s < 4; ++s) {
    int u = t + 256 * s;
    int rc = u >> 5, cl = u & 31;            // rc: channel, cl: position
    float v = 0.f;
    if (l0 + cl < LL) v = x[((size_t)b * CCH + c0 + rc) * LL + l0 + cl];
    float t1 = tanhf(v);
    zs[0][rc][cl] = t1;
    zs[1][rc][cl] = 2.f * t1 * t1 - 1.f;
    zs[2][rc][cl] = t1 * (4.f * t1 * t1 - 3.f);
  }
  __syncthreads();
#pragma unroll
  for (int s = 0; s < 12; ++s) {
    int w = t + 256 * s;                     // 32 rows x 96 cols
    int rl = w / 96, cc = w % 96;
    if (l0 + rl < LL) {
      int cl2 = cc / 3, dm1 = cc % 3;
      float v = zs[dm1][cl2][rl];
      unsigned short hi = f2bf(v);
      unsigned short lo = f2bf(v - bf2f(hi));
      size_t row = (size_t)b * L199 + 1 + l0 + rl;
      Zhi[row * KC + c0 * 3 + cc] = hi;
      Zlo[row * KC + c0 * 3 + cc] = lo;
    }
  }
}

__global__ void zero_zpad(unsigned short* __restrict__ Zhi, unsigned short* __restrict__ Zlo) {
  int u = blockIdx.x * 256 + threadIdx.x;    // 132 rows * 2304
  if (u >= 132 * KC) return;
  int rowi = u / KC, c = u % KC;
  size_t r = (rowi < 128) ? ((size_t)(rowi >> 1) * L199 + (size_t)(rowi & 1) * 198)
                          : ((size_t)NVALID + rowi - 128);   // 12736..12739
  Zhi[r * KC + c] = 0;
  Zlo[r * KC + c] = 0;
}

#define GLL(SRC, DST) \
  __builtin_amdgcn_global_load_lds( \
      (const __attribute__((address_space(1))) void*)(SRC), \
      (__attribute__((address_space(3))) void*)(DST), 16, 0, 0)

// ---- merged GEMM: 256x256 tile, 512 threads (8 waves, 2M x 4N), BK=32,
// double-buffered 128 KB LDS, 32x32x16 MFMA, 4-SUB-PHASE schedule per K-step
// (R6-proven: 1048/1062/1058/1052 us, MfmaUtil ~56%). Two structural
// alternatives both measured WORSE: balanced 2-phase (R7: 1425) and
// 256x128/BK=16 2-blocks-per-CU (R12: 1715, FETCH 3x). This is the optimum.
__global__ __launch_bounds__(512, 2) void conv_gemm3(const unsigned short* __restrict__ Apack,
                                                     const unsigned short* __restrict__ Zhi,
                                                     const unsigned short* __restrict__ Zlo,
                                                     const float* __restrict__ bias3,
                                                     float* __restrict__ Oqk,
                                                     float* __restrict__ Ov) {
  __shared__ unsigned short lds[2 * 4 * 8192];   // [buf][Ah|Al|Bh|Bl][8192 halves]
  const int bid = blockIdx.x;                // 450
  const int xcd = bid & 7, loc = bid >> 3;   // xcd 0,1 own 57 wgs; 2..7 own 56
  const int wg = (xcd < 2) ? (xcd * 57 + loc) : (114 + (xcd - 2) * 56 + loc);
  const int n_t = wg / 9, rem = wg % 9;
  const int proj = rem / 3, m_t = rem % 3;
  const int m_blk = m_t * 256, n_blk = n_t * 256;
  const unsigned short* Ahi = Apack + (size_t)proj * 2 * 768 * KTOT;
  const unsigned short* Alo = Ahi + (size_t)768 * KTOT;
  const float* bias3p = bias3 + proj * 2304;
  float* Op = (proj == 2) ? Ov : Oqk + (size_t)proj * NROW * CCH;

  const int t = threadIdx.x;
  const int wave = t >> 6, lane = t & 63;
  const int wm = (wave >> 2) * 128, wn = (wave & 3) * 64;
  f32x16 acc[4][2] = {};

  // fragment lane-term (halves): unit-parity + k-half + row-in-unit
  const int lt = ((lane >> 4) & 1) * 512 + (lane >> 5) * 128 + (lane & 15) * 8;
  const int auoff = (wm >> 4) * 512 + lt;          // A unit base (Ah at 0, Al at +8192)
  const int buoff = (wn >> 4) * 512 + lt;          // B unit base (Bh at +16384, Bl +24576)

  // staging: 64 panel-units of 1 KB (16 rows x 32 halves); wave w owns units
  // w*8..w*8+7 (tile = u>>4: 0=Ah 1=Al 2=Bh 3=Bl). Pair j = units {2j, 2j+1}.
  const int prow = lane & 15;
  const int kch = lane >> 4;
  const unsigned short* srcs[8];
  int doff[8];
#pragma unroll
  for (int j = 0; j < 8; ++j) {
    int u = (wave << 3) + j;
    int tile = u >> 4, p = u & 15;
    doff[j] = tile * 8192 + p * 512;
    int r;
    const unsigned short* g;
    int rs;
    if (tile < 2) {
      r = m_blk + p * 16 + prow;
      g = (tile == 0) ? Ahi : Alo;
      rs = KTOT;
    } else {
      r = n_blk + p * 16 + prow;
      if (r > 12737) r = 12737;              // clamp into zeroed tail (outputs discarded)
      g = (tile == 2) ? Zhi : Zlo;
      rs = KC;
    }
    srcs[j] = g + (size_t)r * rs + kch * 8;
  }

  const int NIT = KTOT / 32;                 // 216
  // prologue: batch -2 (k=0 -> buf0, all 4 pairs) + batch -1 (k=32 -> buf1, pairs 0-2)
#pragma unroll
  for (int j = 0; j < 8; ++j) GLL(srcs[j], lds + doff[j]);
#pragma unroll
  for (int j = 0; j < 6; ++j) GLL(srcs[j] + 32, lds + 32768 + doff[j]);
  asm volatile("s_waitcnt vmcnt(6)\n\ts_barrier" ::: "memory");
  __builtin_amdgcn_sched_barrier(0);

  for (int i = 0; i < NIT; ++i) {
    const unsigned short* lb = lds + ((i & 1) ? 32768 : 0);
    unsigned short* othbuf = lds + ((i & 1) ? 0 : 32768);   // buf[(i+1)&1]
    unsigned short* curbuf = lds + ((i & 1) ? 32768 : 0);   // buf[i&1]
    const int koff_prev = 32 * (i + 1);      // batch i-1 (fills buf[(i+1)&1])
    const int koff_cur  = 32 * (i + 2);      // batch i   (fills buf[i&1])
    const bool stage_prev = (i < NIT - 1);   // batch i-1 valid (<=213)
    const bool stage_cur  = (i < NIT - 2);   // batch i   valid (<=213)

    bf16x8 bh[2][2], bl[2][2];
    bf16x8 ah[2], al[2];

    // ---------- phase 0: B frags + A quad 0; stage batch i-1 pair 3 ----------
#pragma unroll
    for (int ks = 0; ks < 2; ++ks) {
#pragma unroll
      for (int nb = 0; nb < 2; ++nb) {
        bh[nb][ks] = *(const bf16x8*)(lb + 16384 + buoff + nb * 1024 + ks * 256);
        bl[nb][ks] = *(const bf16x8*)(lb + 24576 + buoff + nb * 1024 + ks * 256);
      }
      ah[ks] = *(const bf16x8*)(lb + auoff + ks * 256);
      al[ks] = *(const bf16x8*)(lb + 8192 + auoff + ks * 256);
    }
    if (stage_prev) {
      GLL(srcs[6] + koff_prev, othbuf + doff[6]);
      GLL(srcs[7] + koff_prev, othbuf + doff[7]);
    }
    asm volatile("s_barrier\n\ts_waitcnt lgkmcnt(0)" ::: "memory");
    __builtin_amdgcn_sched_barrier(0);
    __builtin_amdgcn_s_setprio(1);
#pragma unroll
    for (int p = 0; p < 3; ++p)
#pragma unroll
      for (int ks = 0; ks < 2; ++ks)
#pragma unroll
        for (int nb = 0; nb < 2; ++nb) {
          acc[0][nb] = __builtin_amdgcn_mfma_f32_32x32x16_bf16(
              p == 2 ? al[ks] : ah[ks], p == 1 ? bl[nb][ks] : bh[nb][ks], acc[0][nb], 0, 0, 0);
        }
    __builtin_amdgcn_s_setprio(0);
    asm volatile("s_barrier" ::: "memory");
    __builtin_amdgcn_sched_barrier(0);

    // ---------- phases 1..3: A quad q; stage batch i pair (q-1) ----------
#define PHASEQ(Q)                                                                 \
    {                                                                             \
      _Pragma("unroll") for (int ks = 0; ks < 2; ++ks) {                          \
        ah[ks] = *(const bf16x8*)(lb + auoff + (Q) * 1024 + ks * 256);            \
        al[ks] = *(const bf16x8*)(lb + 8192 + auoff + (Q) * 1024 + ks * 256);     \
      }                                                                           \
      if (stage_cur) {                                                            \
        GLL(srcs[2 * ((Q) - 1)] + koff_cur, curbuf + doff[2 * ((Q) - 1)]);        \
        GLL(srcs[2 * ((Q) - 1) + 1] + koff_cur, curbuf + doff[2 * ((Q) - 1) + 1]);\
      }                                                                           \
      asm volatile("s_barrier\n\ts_waitcnt lgkmcnt(0)" ::: "memory");             \
      __builtin_amdgcn_sched_barrier(0);                                          \
      __builtin_amdgcn_s_setprio(1);                                              \
      _Pragma("unroll") for (int p = 0; p < 3; ++p)                               \
      _Pragma("unroll") for (int ks = 0; ks < 2; ++ks)                            \
      _Pragma("unroll") for (int nb = 0; nb < 2; ++nb) {                          \
        acc[Q][nb] = __builtin_amdgcn_mfma_f32_32x32x16_bf16(                     \
            p == 2 ? al[ks] : ah[ks], p == 1 ? bl[nb][ks] : bh[nb][ks],           \
            acc[Q][nb], 0, 0, 0);                                                 \
      }                                                                           \
      __builtin_amdgcn_s_setprio(0);                                              \
    }

    PHASEQ(1)
    asm volatile("s_barrier" ::: "memory");
    __builtin_amdgcn_sched_barrier(0);
    PHASEQ(2)
    asm volatile("s_barrier" ::: "memory");
    __builtin_amdgcn_sched_barrier(0);
    PHASEQ(3)
    // end-of-step: counted drain (batch i-1 complete for step i+1) + barrier
    if (i < NIT - 2) {
      asm volatile("s_waitcnt vmcnt(6)\n\ts_barrier" ::: "memory");
    } else if (i == NIT - 2) {
      asm volatile("s_waitcnt vmcnt(0)\n\ts_barrier" ::: "memory");
    }
    __builtin_amdgcn_sched_barrier(0);
#undef PHASEQ
  }

  int rowarr[2];
  bool val[2], v0[2], v2[2];
#pragma unroll
  for (int nb = 0; nb < 2; ++nb) {
    int n = n_blk + wn + nb * 32 + (lane & 31);
    int b = n / L199, nl = n - b * L199;
    val[nb] = (n < NVALID) && (nl < LL);
    rowarr[nb] = b * LL + nl;
    v0[nb] = (nl == 0);
    v2[nb] = (nl == 196);
  }
#pragma unroll
  for (int mb = 0; mb < 4; ++mb) {
#pragma unroll
    for (int q = 0; q < 4; ++q) {
      int m = m_blk + wm + mb * 32 + q * 8 + (lane >> 5) * 4;
      f32x4 b0 = *(const f32x4*)(bias3p + m);
      f32x4 b1 = *(const f32x4*)(bias3p + 768 + m);
      f32x4 b2 = *(const f32x4*)(bias3p + 1536 + m);
      f32x4 bs = b0 + b1 + b2;
#pragma unroll
      for (int nb = 0; nb < 2; ++nb) {
        if (val[nb]) {
          f32x4 r;
          r[0] = acc[mb][nb][q * 4 + 0];
          r[1] = acc[mb][nb][q * 4 + 1];
          r[2] = acc[mb][nb][q * 4 + 2];
          r[3] = acc[mb][nb][q * 4 + 3];
          r += bs;
          if (v0[nb]) r -= b0;
          if (v2[nb]) r -= b2;
          *(f32x4*)(Op + (size_t)rowarr[nb] * CCH + m) = r;
        }
      }
    }
  }
}

// ---- BN stats over 12608 rows per proj
__global__ void zero_f32(float* __restrict__ p, int n) {
  int u = blockIdx.x * 256 + threadIdx.x;
  if (u < n) p[u] = 0.f;
}

__global__ void bn_stats(const float* __restrict__ Oqk, const float* __restrict__ Ov,
                         float* __restrict__ Ssum, float* __restrict__ Ssq) {
  int proj = blockIdx.z;
  int cb = blockIdx.x * 64;
  int rb = blockIdx.y;                         // 32 chunks of 394 rows
  int t = threadIdx.x;
  int ch = cb + (t & 63);
  int phase = t >> 6;
  const float* Op = (proj == 2) ? Ov : Oqk + (size_t)proj * NROW * CCH;
  float s = 0.f, q = 0.f;
  for (int r = rb * 394 + phase; r < rb * 394 + 394; r += 4) {
    float v = Op[(size_t)r * CCH + ch];
    s += v; q += v * v;
  }
  __shared__ float rs[256], rq[256];
  rs[t] = s; rq[t] = q;
  __syncthreads();
  if (t < 64) {
    float S = rs[t] + rs[t + 64] + rs[t + 128] + rs[t + 192];
    float Q = rq[t] + rq[t + 64] + rq[t + 128] + rq[t + 192];
    atomicAdd(&Ssum[proj * CCH + cb + t], S);
    atomicAdd(&Ssq[proj * CCH + cb + t], Q);
  }
}

__global__ void bn_fin(const float* __restrict__ Ssum, const float* __restrict__ Ssq,
                       const float* __restrict__ sq, const float* __restrict__ bq,
                       const float* __restrict__ sk, const float* __restrict__ bk,
                       const float* __restrict__ sv, const float* __restrict__ bv,
                       float* __restrict__ abn) {
  int u = blockIdx.x * 256 + threadIdx.x;
  if (u >= 3 * CCH) return;
  int proj = u / CCH, ch = u % CCH;
  float mean = Ssum[u] / 12608.f;
  float var = Ssq[u] / 12608.f - mean * mean;
  const float* sc = proj == 0 ? sq : (proj == 1 ? sk : sv);
  const float* bi = proj == 0 ? bq : (proj == 1 ? bk : bv);
  float a = sc[ch] * rsqrtf(var + 1e-5f);
  abn[u * 2] = a;
  abn[u * 2 + 1] = bi[ch] - mean * a;
}

// ---- BN-affine + RoPE -> Qr,Kr (b,l,768)
__global__ void rope_pack(const float* __restrict__ Oqk, const float* __restrict__ abn,
                          const float* __restrict__ freqs, float* __restrict__ Qr,
                          float* __restrict__ Kr) {
  size_t u = (size_t)blockIdx.x * 256 + threadIdx.x;    // 64*197*384
  if (u >= 64ull * LL * 384) return;
  int c2 = (int)(u % 384);
  int l = (int)((u / 384) % LL);
  int b = (int)(u / (384ull * LL));
  size_t rowO = ((size_t)b * LL + l) * CCH + 2 * c2;
  const float* Ok = Oqk + (size_t)NROW * CCH;
  float q0 = Oqk[rowO], q1 = Oqk[rowO + 1];
  float k0 = Ok[rowO], k1 = Ok[rowO + 1];
  float aq0 = abn[(2 * c2) * 2],                bq0 = abn[(2 * c2) * 2 + 1];
  float aq1 = abn[(2 * c2 + 1) * 2],            bq1 = abn[(2 * c2 + 1) * 2 + 1];
  float ak0 = abn[(CCH + 2 * c2) * 2],          bk0 = abn[(CCH + 2 * c2) * 2 + 1];
  float ak1 = abn[(CCH + 2 * c2 + 1) * 2],      bk1 = abn[(CCH + 2 * c2 + 1) * 2 + 1];
  q0 = q0 * aq0 + bq0; q1 = q1 * aq1 + bq1;
  k0 = k0 * ak0 + bk0; k1 = k1 * ak1 + bk1;
  if (l > 0) {
    int tt = l - 1;
    float tx = (float)(tt % 14), ty = (float)(tt / 14);
    float ang = tx * freqs[c2] + ty * freqs[384 + c2];
    float sn, cs;
    sincosf(ang, &sn, &cs);
    float r0 = q0 * cs - q1 * sn, r1 = q0 * sn + q1 * cs;
    q0 = r0; q1 = r1;
    r0 = k0 * cs - k1 * sn; r1 = k0 * sn + k1 * cs;
    k0 = r0; k1 = r1;
  }
  size_t rowT = ((size_t)b * LL + l) * CCH + 2 * c2;
  Qr[rowT] = q0; Qr[rowT + 1] = q1;
  Kr[rowT] = k0; Kr[rowT + 1] = k1;
}

// ---- energy = Qr Kr^T, 64x64 tile, 16x16 threads, 4x4 register block.
__global__ void energy_k(const float* __restrict__ Qr, const float* __restrict__ Kr,
                         float* __restrict__ E) {
  __shared__ float Qs[64][33], Ks[64][33];
  int i0 = blockIdx.x * 64, j0 = blockIdx.y * 64, b = blockIdx.z;
  int t = threadIdx.x, tj = t & 15, ti = t >> 4;
  float acc[4][4] = {};
  const float* Qb = Qr + (size_t)b * LL * CCH;
  const float* Kb = Kr + (size_t)b * LL * CCH;
  for (int k0 = 0; k0 < CCH; k0 += 32) {
    __syncthreads();
#pragma unroll
    for (int s = 0; s < 8; ++s) {
      int u = t + 256 * s, r = u >> 5, cc = u & 31;
      Qs[r][cc] = (i0 + r < LL) ? Qb[(size_t)(i0 + r) * CCH + k0 + cc] : 0.f;
      Ks[r][cc] = (j0 + r < LL) ? Kb[(size_t)(j0 + r) * CCH + k0 + cc] : 0.f;
    }
    __syncthreads();
#pragma unroll
    for (int kk = 0; kk < 32; ++kk) {
      float qv[4], kv[4];
#pragma unroll
      for (int q = 0; q < 4; ++q) qv[q] = Qs[ti * 4 + q][kk];
#pragma unroll
      for (int j = 0; j < 4; ++j) kv[j] = Ks[tj * 4 + j][kk];
#pragma unroll
      for (int q = 0; q < 4; ++q)
#pragma unroll
        for (int j = 0; j < 4; ++j) acc[q][j] += qv[q] * kv[j];
    }
  }
#pragma unroll
  for (int q = 0; q < 4; ++q) {
    int i = i0 + ti * 4 + q;
    if (i >= LL) continue;
#pragma unroll
    for (int j = 0; j < 4; ++j) {
      int jj = j0 + tj * 4 + j;
      if (jj < LL) E[((size_t)b * LL + i) * LL + jj] = acc[q][j];
    }
  }
}

__global__ void softmax_k(float* __restrict__ E) {
  int row = blockIdx.x;                // 64*197
  int lane = threadIdx.x;              // 64
  float* Er = E + (size_t)row * LL;
  float v[4];
  float m = -3.4e38f;
#pragma unroll
  for (int q = 0; q < 4; ++q) {
    int j = lane + 64 * q;
    v[q] = (j < LL) ? Er[j] : -3.4e38f;
    m = fmaxf(m, v[q]);
  }
  for (int off = 32; off; off >>= 1) m = fmaxf(m, __shfl_down(m, off));
  m = __shfl(m, 0);
  float s = 0.f;
#pragma unroll
  for (int q = 0; q < 4; ++q) {
    int j = lane + 64 * q;
    v[q] = (j < LL) ? expf(v[q] - m) : 0.f;
    s += v[q];
  }
  for (int off = 32; off; off >>= 1) s += __shfl_down(s, off);
  s = __shfl(s, 0);
  float inv = 1.f / s;
#pragma unroll
  for (int q = 0; q < 4; ++q) {
    int j = lane + 64 * q;
    if (j < LL) Er[j] = v[q] * inv;
  }
}

// ---- fused AV + transpose: Y(b, c, i) = gamma*x + (a*[att@V] + b)^T.
__global__ void av_y(const float* __restrict__ att, const float* __restrict__ Ov,
                     const float* __restrict__ abn, const float* __restrict__ x,
                     const float* __restrict__ gamma, float* __restrict__ Y) {
  __shared__ float As[32][33];
  __shared__ float Vs[32][128];
  __shared__ float Ts[32][129];
  int i0 = blockIdx.x * 32, c0 = blockIdx.y * 128, b = blockIdx.z;
  int t = threadIdx.x, tc = t & 63, tq = t >> 6;
  const float* attb = att + (size_t)b * LL * LL;
  float acc[8][2] = {};
  for (int j0 = 0; j0 < LL; j0 += 32) {
    __syncthreads();
#pragma unroll
    for (int s = 0; s < 4; ++s) {
      int u = t + 256 * s, r = u >> 5, cc = u & 31;
      As[r][cc] = (i0 + r < LL && j0 + cc < LL) ? attb[(size_t)(i0 + r) * LL + j0 + cc] : 0.f;
    }
#pragma unroll
    for (int s = 0; s < 16; ++s) {
      int u = t + 256 * s, r = u >> 7, cc = u & 127;
      Vs[r][cc] = (j0 + r < LL) ? Ov[((size_t)b * LL + j0 + r) * CCH + c0 + cc] : 0.f;
    }
    __syncthreads();
#pragma unroll
    for (int jj = 0; jj < 32; ++jj) {
      f32x2 vv = *(const f32x2*)&Vs[jj][2 * tc];
#pragma unroll
      for (int q = 0; q < 8; ++q) {
        float a = As[tq * 8 + q][jj];
        acc[q][0] += a * vv[0];
        acc[q][1] += a * vv[1];
      }
    }
  }
  int c = c0 + 2 * tc;
  float a0 = abn[(2 * CCH + c) * 2],     b0 = abn[(2 * CCH + c) * 2 + 1];
  float a1 = abn[(2 * CCH + c + 1) * 2], b1 = abn[(2 * CCH + c + 1) * 2 + 1];
#pragma unroll
  for (int q = 0; q < 8; ++q) {
    int il = tq * 8 + q;
    Ts[il][2 * tc] = a0 * acc[q][0] + b0;
    Ts[il][2 * tc + 1] = a1 * acc[q][1] + b1;
  }
  __syncthreads();
  float g = gamma[0];
#pragma unroll
  for (int s = 0; s < 16; ++s) {
    int u = t + 256 * s, cc = u >> 5, il = u & 31;   // cc: 0..127, il: 0..31
    if (i0 + il < LL) {
      size_t idx = ((size_t)b * CCH + c0 + cc) * LL + i0 + il;
      Y[idx] = g * x[idx] + Ts[il][cc];
    }
  }
}

// ---- fused BN(Y) + apply
__global__ void bn_y_final(const float* __restrict__ Y, const float* __restrict__ ns,
                           const float* __restrict__ nb, float* __restrict__ out) {
  __shared__ float ych[12608];
  __shared__ float rs[256], rq[256];
  int c = blockIdx.x;
  int t = threadIdx.x;
  float s = 0.f, q = 0.f;
  for (int u = t; u < 12608; u += 256) {
    int b = u / LL, l = u - b * LL;
    float v = Y[((size_t)b * CCH + c) * LL + l];
    ych[u] = v;
    s += v; q += v * v;
  }
  rs[t] = s; rq[t] = q;
  __syncthreads();
  for (int off = 128; off; off >>= 1) {
    if (t < off) { rs[t] += rs[t + off]; rq[t] += rq[t + off]; }
    __syncthreads();
  }
  float mean = rs[0] / 12608.f, var = rq[0] / 12608.f - mean * mean;
  float a = ns[c] * rsqrtf(var + 1e-5f);
  float bb = nb[c] - mean * a;
  for (int u = t; u < 12608; u += 256) {
    int b = u / LL, l = u - b * LL;
    out[((size_t)b * CCH + c) * LL + l] = a * ych[u] + bb;
  }
}

extern "C" void kernel_launch(void* const* d_in, const int* in_sizes, int n_in,
                              void* d_out, int out_size, void* d_ws, size_t ws_size,
                              hipStream_t stream) {
  const float* x = (const float*)d_in[0];
  const float* Wq = (const float*)d_in[1];
  const float* Wk = (const float*)d_in[2];
  const float* Wv = (const float*)d_in[3];
  const float* bnq_s = (const float*)d_in[4];
  const float* bnq_b = (const float*)d_in[5];
  const float* bnk_s = (const float*)d_in[6];
  const float* bnk_b = (const float*)d_in[7];
  const float* bnv_s = (const float*)d_in[8];
  const float* bnv_b = (const float*)d_in[9];
  const float* gamma = (const float*)d_in[10];
  const float* freqs = (const float*)d_in[11];
  const float* norm_s = (const float*)d_in[12];
  const float* norm_b = (const float*)d_in[13];
  float* out = (float*)d_out;

  char* ws = (char*)d_ws;
  const size_t QRSZ  = 38731776;                 // 64*197*768*4
  const size_t PACK1 = 21233664;                 // per-proj Ahi+Alo bytes
  const size_t ZSZ   = 58705920;                 // 12740*2304*2

  const size_t OFS_PACK = 0;
  const size_t OFS_Z    = 3 * PACK1;
  const size_t OFS_ZLO  = OFS_Z + ZSZ;
  const size_t OFS_O    = OFS_ZLO + ZSZ;
  const size_t OFS_MISC = OFS_O + 2 * QRSZ;

  unsigned short* Apack = (unsigned short*)(ws + OFS_PACK);
  unsigned short* Zhi = (unsigned short*)(ws + OFS_Z);
  unsigned short* Zlo = (unsigned short*)(ws + OFS_ZLO);
  float* Oqk = (float*)(ws + OFS_O);
  float* bias3 = (float*)(ws + OFS_MISC);              // 27,648 B
  float* Ssum = (float*)(ws + OFS_MISC + 27648);       // 9,216 B
  float* Ssq  = (float*)(ws + OFS_MISC + 36864);       // 9,216 B
  float* abn  = (float*)(ws + OFS_MISC + 46080);       // 18,432 B
  // V lives in d_out until av_y consumes it; bn_y_final overwrites afterwards.
  float* Ov = out;
  // post-GEMM reuse of the Z region (Z dead after the GEMM launch):
  float* Qr = (float*)(ws + OFS_Z);                    // [0, QRSZ)
  float* Kr = (float*)(ws + OFS_Z + QRSZ);             // [QRSZ, 2*QRSZ)
  float* E  = (float*)(ws + OFS_Z + 2 * QRSZ);         // 9,935,104 B
  float* Y  = (float*)(ws + OFS_Z + QRSZ);             // after energy_k (Kr dead)

  zero_zpad<<<dim3((132 * KC + 255) / 256), 256, 0, stream>>>(Zhi, Zlo);
  z_kernel<<<dim3(24, 7, 64), 256, 0, stream>>>(x, Zhi, Zlo);
  pack_bias<<<dim3(2304), 256, 0, stream>>>(Wq, Wk, Wv, Apack, bias3, PACK1 / 2);
  conv_gemm3<<<dim3(450), 512, 0, stream>>>(Apack, Zhi, Zlo, bias3, Oqk, Ov);

  zero_f32<<<dim3(18), 256, 0, stream>>>(Ssum, 4608);   // Ssum+Ssq contiguous
  bn_stats<<<dim3(12, 32, 3), 256, 0, stream>>>(Oqk, Ov, Ssum, Ssq);
  bn_fin<<<dim3(9), 256, 0, stream>>>(Ssum, Ssq, bnq_s, bnq_b, bnk_s, bnk_b, bnv_s, bnv_b, abn);
  rope_pack<<<dim3((unsigned)((64ull * LL * 384 + 255) / 256)), 256, 0, stream>>>(Oqk, abn, freqs, Qr, Kr);
  energy_k<<<dim3(4, 4, 64), 256, 0, stream>>>(Qr, Kr, E);
  softmax_k<<<dim3(64 * LL), 64, 0, stream>>>(E);
  av_y<<<dim3(7, 6, 64), 256, 0, stream>>>(E, Ov, abn, x, gamma, Y);
  bn_y_final<<<dim3(CCH), 256, 0, stream>>>(Y, norm_s, norm_b, out);
}

// Round 14
// 1825.144 us; speedup vs baseline: 1.3819x; 1.0587x over previous
//
#include <hip/hip_runtime.h>

#define CCH 768
#define LL  197
#define L199 199
#define KC  2304          // K per tap (T0 dropped)
#define KTOT 6912         // 3 taps fused along K
#define MK2 1769472       // 768*2304
#define NVALID 12736      // 64*199 GEMM row space
#define NROW 12608        // 64*197 valid rows (compacted)

typedef __bf16 bf16x8 __attribute__((ext_vector_type(8)));
typedef float f32x2 __attribute__((ext_vector_type(2)));
typedef float f32x4 __attribute__((ext_vector_type(4)));
typedef float f32x16 __attribute__((ext_vector_type(16)));

__device__ __forceinline__ unsigned short f2bf(float f) {
  unsigned int u = __float_as_uint(f);
  u += 0x7FFFu + ((u >> 16) & 1u);           // RNE
  return (unsigned short)(u >> 16);
}
__device__ __forceinline__ float bf2f(unsigned short h) {
  return __uint_as_float(((unsigned int)h) << 16);
}

// ---- fused weight pack + d0 bias (R10-proven)
__global__ void pack_bias(const float* __restrict__ Wq, const float* __restrict__ Wk,
                          const float* __restrict__ Wv, unsigned short* __restrict__ Apack,
                          float* __restrict__ bias3, size_t pack1_halves) {
  __shared__ float wrow[9216];               // 3072*3 floats = 36 KB
  __shared__ float red0[256], red1[256], red2[256];
  const int bid = blockIdx.x;                // 2304 = 3*768
  const int proj = bid / 768, m = bid % 768;
  const int t = threadIdx.x;
  const float* W = proj == 0 ? Wq : (proj == 1 ? Wk : Wv);
  const float* src = W + (size_t)m * 9216;
#pragma unroll
  for (int s = 0; s < 36; ++s) wrow[t + 256 * s] = src[t + 256 * s];
  __syncthreads();
  float s0 = 0.f, s1 = 0.f, s2 = 0.f;
  for (int c = t; c < 768; c += 256) {
    s0 += wrow[12 * c];
    s1 += wrow[12 * c + 1];
    s2 += wrow[12 * c + 2];
  }
  red0[t] = s0; red1[t] = s1; red2[t] = s2;
  unsigned short* Ahi = Apack + (size_t)proj * pack1_halves;
  unsigned short* Alo = Ahi + (size_t)768 * KTOT;
#pragma unroll
  for (int s = 0; s < 9; ++s) {
    int u = t + 256 * s;                     // 0..2303
    int c = u / 3, dm1 = u % 3;
    int ci = c * 4 + dm1 + 1;
#pragma unroll
    for (int tap = 0; tap < 3; ++tap) {
      float f = wrow[ci * 3 + tap];
      unsigned short hi = f2bf(f);
      unsigned short lo = f2bf(f - bf2f(hi));
      size_t idx = (size_t)m * KTOT + tap * KC + u;
      Ahi[idx] = hi;
      Alo[idx] = lo;
    }
  }
  __syncthreads();
  for (int off = 128; off; off >>= 1) {
    if (t < off) {
      red0[t] += red0[t + off];
      red1[t] += red1[t + off];
      red2[t] += red2[t + off];
    }
    __syncthreads();
  }
  if (t == 0) {
    bias3[proj * 2304 + m] = red0[0];
    bias3[proj * 2304 + 768 + m] = red1[0];
    bias3[proj * 2304 + 1536 + m] = red2[0];
  }
}

// ---- z: T_{1..3}(tanh(x)) -> Z (12740 rows, 2304) hi/lo bf16; row = b*199 + 1 + l
__global__ void z_kernel(const float* __restrict__ x, unsigned short* __restrict__ Zhi,
                         unsigned short* __restrict__ Zlo) {
  __shared__ float zs[3][32][33];
  int c0 = blockIdx.x * 32, l0 = blockIdx.y * 32, b = blockIdx.z;
  int t = threadIdx.x;
#pragma unroll
  for (int s = 0; s < 4; ++s) {
    int u = t + 256 * s;
    int rc = u >> 5, cl = u & 31;            // rc: channel, cl: position
    float v = 0.f;
    if (l0 + cl < LL) v = x[((size_t)b * CCH + c0 + rc) * LL + l0 + cl];
    float t1 = tanhf(v);
    zs[0][rc][cl] = t1;
    zs[1][rc][cl] = 2.f * t1 * t1 - 1.f;
    zs[2][rc][cl] = t1 * (4.f * t1 * t1 - 3.f);
  }
  __syncthreads();
#pragma unroll
  for (int s = 0; s < 12; ++s) {
    int w = t + 256 * s;                     // 32 rows x 96 cols
    int rl = w / 96, cc = w % 96;
    if (l0 + rl < LL) {
      int cl2 = cc / 3, dm1 = cc % 3;
      float v = zs[dm1][cl2][rl];
      unsigned short hi = f2bf(v);
      unsigned short lo = f2bf(v - bf2f(hi));
      size_t row = (size_t)b * L199 + 1 + l0 + rl;
      Zhi[row * KC + c0 * 3 + cc] = hi;
      Zlo[row * KC + c0 * 3 + cc] = lo;
    }
  }
}

__global__ void zero_zpad(unsigned short* __restrict__ Zhi, unsigned short* __restrict__ Zlo) {
  int u = blockIdx.x * 256 + threadIdx.x;    // 132 rows * 2304
  if (u >= 132 * KC) return;
  int rowi = u / KC, c = u % KC;
  size_t r = (rowi < 128) ? ((size_t)(rowi >> 1) * L199 + (size_t)(rowi & 1) * 198)
                          : ((size_t)NVALID + rowi - 128);   // 12736..12739
  Zhi[r * KC + c] = 0;
  Zlo[r * KC + c] = 0;
}

#define GLL(SRC, DST) \
  __builtin_amdgcn_global_load_lds( \
      (const __attribute__((address_space(1))) void*)(SRC), \
      (__attribute__((address_space(3))) void*)(DST), 16, 0, 0)

// ---- merged GEMM: 256x256 tile, 512 threads (8 waves, 2M x 4N), BK=32,
// double-buffered 128 KB LDS, 32x32x16 MFMA, 4-SUB-PHASE schedule per K-step.
// R13 variant: redundant PRE-barriers removed (8 -> 5 barriers/step).
// Sync invariants carried by: (a) the post-MFMA barrier of each phase --
// every wave's lgkm(0) preceded its MFMAs, so the barrier certifies phase-Q
// reads complete block-wide BEFORE phase Q+1's staging overwrites that
// region; (b) the step-end counted vmcnt(6)+barrier -- batch i-1 landed
// block-wide before step i+1 reads it. GLL placement identical to R6
// (distributed 2/phase); only barrier count changes.
__global__ __launch_bounds__(512, 2) void conv_gemm3(const unsigned short* __restrict__ Apack,
                                                     const unsigned short* __restrict__ Zhi,
                                                     const unsigned short* __restrict__ Zlo,
                                                     const float* __restrict__ bias3,
                                                     float* __restrict__ Oqk,
                                                     float* __restrict__ Ov) {
  __shared__ unsigned short lds[2 * 4 * 8192];   // [buf][Ah|Al|Bh|Bl][8192 halves]
  const int bid = blockIdx.x;                // 450
  const int xcd = bid & 7, loc = bid >> 3;   // xcd 0,1 own 57 wgs; 2..7 own 56
  const int wg = (xcd < 2) ? (xcd * 57 + loc) : (114 + (xcd - 2) * 56 + loc);
  const int n_t = wg / 9, rem = wg % 9;
  const int proj = rem / 3, m_t = rem % 3;
  const int m_blk = m_t * 256, n_blk = n_t * 256;
  const unsigned short* Ahi = Apack + (size_t)proj * 2 * 768 * KTOT;
  const unsigned short* Alo = Ahi + (size_t)768 * KTOT;
  const float* bias3p = bias3 + proj * 2304;
  float* Op = (proj == 2) ? Ov : Oqk + (size_t)proj * NROW * CCH;

  const int t = threadIdx.x;
  const int wave = t >> 6, lane = t & 63;
  const int wm = (wave >> 2) * 128, wn = (wave & 3) * 64;
  f32x16 acc[4][2] = {};

  // fragment lane-term (halves): unit-parity + k-half + row-in-unit
  const int lt = ((lane >> 4) & 1) * 512 + (lane >> 5) * 128 + (lane & 15) * 8;
  const int auoff = (wm >> 4) * 512 + lt;          // A unit base (Ah at 0, Al at +8192)
  const int buoff = (wn >> 4) * 512 + lt;          // B unit base (Bh at +16384, Bl +24576)

  // staging: 64 panel-units of 1 KB (16 rows x 32 halves); wave w owns units
  // w*8..w*8+7 (tile = u>>4: 0=Ah 1=Al 2=Bh 3=Bl). Pair j = units {2j, 2j+1}.
  const int prow = lane & 15;
  const int kch = lane >> 4;
  const unsigned short* srcs[8];
  int doff[8];
#pragma unroll
  for (int j = 0; j < 8; ++j) {
    int u = (wave << 3) + j;
    int tile = u >> 4, p = u & 15;
    doff[j] = tile * 8192 + p * 512;
    int r;
    const unsigned short* g;
    int rs;
    if (tile < 2) {
      r = m_blk + p * 16 + prow;
      g = (tile == 0) ? Ahi : Alo;
      rs = KTOT;
    } else {
      r = n_blk + p * 16 + prow;
      if (r > 12737) r = 12737;              // clamp into zeroed tail (outputs discarded)
      g = (tile == 2) ? Zhi : Zlo;
      rs = KC;
    }
    srcs[j] = g + (size_t)r * rs + kch * 8;
  }

  const int NIT = KTOT / 32;                 // 216
  // prologue: batch -2 (k=0 -> buf0, all 4 pairs) + batch -1 (k=32 -> buf1, pairs 0-2)
#pragma unroll
  for (int j = 0; j < 8; ++j) GLL(srcs[j], lds + doff[j]);
#pragma unroll
  for (int j = 0; j < 6; ++j) GLL(srcs[j] + 32, lds + 32768 + doff[j]);
  asm volatile("s_waitcnt vmcnt(6)\n\ts_barrier" ::: "memory");
  __builtin_amdgcn_sched_barrier(0);

  for (int i = 0; i < NIT; ++i) {
    const unsigned short* lb = lds + ((i & 1) ? 32768 : 0);
    unsigned short* othbuf = lds + ((i & 1) ? 0 : 32768);   // buf[(i+1)&1]
    unsigned short* curbuf = lds + ((i & 1) ? 32768 : 0);   // buf[i&1]
    const int koff_prev = 32 * (i + 1);      // batch i-1 (fills buf[(i+1)&1])
    const int koff_cur  = 32 * (i + 2);      // batch i   (fills buf[i&1])
    const bool stage_prev = (i < NIT - 1);   // batch i-1 valid (<=213)
    const bool stage_cur  = (i < NIT - 2);   // batch i   valid (<=213)

    bf16x8 bh[2][2], bl[2][2];
    bf16x8 ah[2], al[2];

    // ---------- phase 0: B frags + A quad 0; stage batch i-1 pair 3 ----------
#pragma unroll
    for (int ks = 0; ks < 2; ++ks) {
#pragma unroll
      for (int nb = 0; nb < 2; ++nb) {
        bh[nb][ks] = *(const bf16x8*)(lb + 16384 + buoff + nb * 1024 + ks * 256);
        bl[nb][ks] = *(const bf16x8*)(lb + 24576 + buoff + nb * 1024 + ks * 256);
      }
      ah[ks] = *(const bf16x8*)(lb + auoff + ks * 256);
      al[ks] = *(const bf16x8*)(lb + 8192 + auoff + ks * 256);
    }
    if (stage_prev) {
      GLL(srcs[6] + koff_prev, othbuf + doff[6]);
      GLL(srcs[7] + koff_prev, othbuf + doff[7]);
    }
    asm volatile("s_waitcnt lgkmcnt(0)" ::: "memory");
    __builtin_amdgcn_sched_barrier(0);
    __builtin_amdgcn_s_setprio(1);
#pragma unroll
    for (int p = 0; p < 3; ++p)
#pragma unroll
      for (int ks = 0; ks < 2; ++ks)
#pragma unroll
        for (int nb = 0; nb < 2; ++nb) {
          acc[0][nb] = __builtin_amdgcn_mfma_f32_32x32x16_bf16(
              p == 2 ? al[ks] : ah[ks], p == 1 ? bl[nb][ks] : bh[nb][ks], acc[0][nb], 0, 0, 0);
        }
    __builtin_amdgcn_s_setprio(0);
    asm volatile("s_barrier" ::: "memory");   // phase-0 reads complete block-wide
    __builtin_amdgcn_sched_barrier(0);

    // ---------- phases 1..3: A quad q; stage batch i pair (q-1) ----------
#define PHASEQ(Q)                                                                 \
    {                                                                             \
      _Pragma("unroll") for (int ks = 0; ks < 2; ++ks) {                          \
        ah[ks] = *(const bf16x8*)(lb + auoff + (Q) * 1024 + ks * 256);            \
        al[ks] = *(const bf16x8*)(lb + 8192 + auoff + (Q) * 1024 + ks * 256);     \
      }                                                                           \
      if (stage_cur) {                                                            \
        GLL(srcs[2 * ((Q) - 1)] + koff_cur, curbuf + doff[2 * ((Q) - 1)]);        \
        GLL(srcs[2 * ((Q) - 1) + 1] + koff_cur, curbuf + doff[2 * ((Q) - 1) + 1]);\
      }                                                                           \
      asm volatile("s_waitcnt lgkmcnt(0)" ::: "memory");                          \
      __builtin_amdgcn_sched_barrier(0);                                          \
      __builtin_amdgcn_s_setprio(1);                                              \
      _Pragma("unroll") for (int p = 0; p < 3; ++p)                               \
      _Pragma("unroll") for (int ks = 0; ks < 2; ++ks)                            \
      _Pragma("unroll") for (int nb = 0; nb < 2; ++nb) {                          \
        acc[Q][nb] = __builtin_amdgcn_mfma_f32_32x32x16_bf16(                     \
            p == 2 ? al[ks] : ah[ks], p == 1 ? bl[nb][ks] : bh[nb][ks],           \
            acc[Q][nb], 0, 0, 0);                                                 \
      }                                                                           \
      __builtin_amdgcn_s_setprio(0);                                              \
    }

    PHASEQ(1)
    asm volatile("s_barrier" ::: "memory");   // phase-1 reads complete block-wide
    __builtin_amdgcn_sched_barrier(0);
    PHASEQ(2)
    asm volatile("s_barrier" ::: "memory");   // phase-2 reads complete block-wide
    __builtin_amdgcn_sched_barrier(0);
    PHASEQ(3)
    // end-of-step: counted drain (batch i-1 complete for step i+1) + barrier
    if (i < NIT - 2) {
      asm volatile("s_waitcnt vmcnt(6)\n\ts_barrier" ::: "memory");
    } else if (i == NIT - 2) {
      asm volatile("s_waitcnt vmcnt(0)\n\ts_barrier" ::: "memory");
    }
    __builtin_amdgcn_sched_barrier(0);
#undef PHASEQ
  }

  int rowarr[2];
  bool val[2], v0[2], v2[2];
#pragma unroll
  for (int nb = 0; nb < 2; ++nb) {
    int n = n_blk + wn + nb * 32 + (lane & 31);
    int b = n / L199, nl = n - b * L199;
    val[nb] = (n < NVALID) && (nl < LL);
    rowarr[nb] = b * LL + nl;
    v0[nb] = (nl == 0);
    v2[nb] = (nl == 196);
  }
#pragma unroll
  for (int mb = 0; mb < 4; ++mb) {
#pragma unroll
    for (int q = 0; q < 4; ++q) {
      int m = m_blk + wm + mb * 32 + q * 8 + (lane >> 5) * 4;
      f32x4 b0 = *(const f32x4*)(bias3p + m);
      f32x4 b1 = *(const f32x4*)(bias3p + 768 + m);
      f32x4 b2 = *(const f32x4*)(bias3p + 1536 + m);
      f32x4 bs = b0 + b1 + b2;
#pragma unroll
      for (int nb = 0; nb < 2; ++nb) {
        if (val[nb]) {
          f32x4 r;
          r[0] = acc[mb][nb][q * 4 + 0];
          r[1] = acc[mb][nb][q * 4 + 1];
          r[2] = acc[mb][nb][q * 4 + 2];
          r[3] = acc[mb][nb][q * 4 + 3];
          r += bs;
          if (v0[nb]) r -= b0;
          if (v2[nb]) r -= b2;
          *(f32x4*)(Op + (size_t)rowarr[nb] * CCH + m) = r;
        }
      }
    }
  }
}

// ---- BN stats over 12608 rows per proj
__global__ void zero_f32(float* __restrict__ p, int n) {
  int u = blockIdx.x * 256 + threadIdx.x;
  if (u < n) p[u] = 0.f;
}

__global__ void bn_stats(const float* __restrict__ Oqk, const float* __restrict__ Ov,
                         float* __restrict__ Ssum, float* __restrict__ Ssq) {
  int proj = blockIdx.z;
  int cb = blockIdx.x * 64;
  int rb = blockIdx.y;                         // 32 chunks of 394 rows
  int t = threadIdx.x;
  int ch = cb + (t & 63);
  int phase = t >> 6;
  const float* Op = (proj == 2) ? Ov : Oqk + (size_t)proj * NROW * CCH;
  float s = 0.f, q = 0.f;
  for (int r = rb * 394 + phase; r < rb * 394 + 394; r += 4) {
    float v = Op[(size_t)r * CCH + ch];
    s += v; q += v * v;
  }
  __shared__ float rs[256], rq[256];
  rs[t] = s; rq[t] = q;
  __syncthreads();
  if (t < 64) {
    float S = rs[t] + rs[t + 64] + rs[t + 128] + rs[t + 192];
    float Q = rq[t] + rq[t + 64] + rq[t + 128] + rq[t + 192];
    atomicAdd(&Ssum[proj * CCH + cb + t], S);
    atomicAdd(&Ssq[proj * CCH + cb + t], Q);
  }
}

__global__ void bn_fin(const float* __restrict__ Ssum, const float* __restrict__ Ssq,
                       const float* __restrict__ sq, const float* __restrict__ bq,
                       const float* __restrict__ sk, const float* __restrict__ bk,
                       const float* __restrict__ sv, const float* __restrict__ bv,
                       float* __restrict__ abn) {
  int u = blockIdx.x * 256 + threadIdx.x;
  if (u >= 3 * CCH) return;
  int proj = u / CCH, ch = u % CCH;
  float mean = Ssum[u] / 12608.f;
  float var = Ssq[u] / 12608.f - mean * mean;
  const float* sc = proj == 0 ? sq : (proj == 1 ? sk : sv);
  const float* bi = proj == 0 ? bq : (proj == 1 ? bk : bv);
  float a = sc[ch] * rsqrtf(var + 1e-5f);
  abn[u * 2] = a;
  abn[u * 2 + 1] = bi[ch] - mean * a;
}

// ---- BN-affine + RoPE -> Qr,Kr (b,l,768)
__global__ void rope_pack(const float* __restrict__ Oqk, const float* __restrict__ abn,
                          const float* __restrict__ freqs, float* __restrict__ Qr,
                          float* __restrict__ Kr) {
  size_t u = (size_t)blockIdx.x * 256 + threadIdx.x;    // 64*197*384
  if (u >= 64ull * LL * 384) return;
  int c2 = (int)(u % 384);
  int l = (int)((u / 384) % LL);
  int b = (int)(u / (384ull * LL));
  size_t rowO = ((size_t)b * LL + l) * CCH + 2 * c2;
  const float* Ok = Oqk + (size_t)NROW * CCH;
  float q0 = Oqk[rowO], q1 = Oqk[rowO + 1];
  float k0 = Ok[rowO], k1 = Ok[rowO + 1];
  float aq0 = abn[(2 * c2) * 2],                bq0 = abn[(2 * c2) * 2 + 1];
  float aq1 = abn[(2 * c2 + 1) * 2],            bq1 = abn[(2 * c2 + 1) * 2 + 1];
  float ak0 = abn[(CCH + 2 * c2) * 2],          bk0 = abn[(CCH + 2 * c2) * 2 + 1];
  float ak1 = abn[(CCH + 2 * c2 + 1) * 2],      bk1 = abn[(CCH + 2 * c2 + 1) * 2 + 1];
  q0 = q0 * aq0 + bq0; q1 = q1 * aq1 + bq1;
  k0 = k0 * ak0 + bk0; k1 = k1 * ak1 + bk1;
  if (l > 0) {
    int tt = l - 1;
    float tx = (float)(tt % 14), ty = (float)(tt / 14);
    float ang = tx * freqs[c2] + ty * freqs[384 + c2];
    float sn, cs;
    sincosf(ang, &sn, &cs);
    float r0 = q0 * cs - q1 * sn, r1 = q0 * sn + q1 * cs;
    q0 = r0; q1 = r1;
    r0 = k0 * cs - k1 * sn; r1 = k0 * sn + k1 * cs;
    k0 = r0; k1 = r1;
  }
  size_t rowT = ((size_t)b * LL + l) * CCH + 2 * c2;
  Qr[rowT] = q0; Qr[rowT + 1] = q1;
  Kr[rowT] = k0; Kr[rowT + 1] = k1;
}

// ---- energy = Qr Kr^T, 64x64 tile, 16x16 threads, 4x4 register block.
__global__ void energy_k(const float* __restrict__ Qr, const float* __restrict__ Kr,
                         float* __restrict__ E) {
  __shared__ float Qs[64][33], Ks[64][33];
  int i0 = blockIdx.x * 64, j0 = blockIdx.y * 64, b = blockIdx.z;
  int t = threadIdx.x, tj = t & 15, ti = t >> 4;
  float acc[4][4] = {};
  const float* Qb = Qr + (size_t)b * LL * CCH;
  const float* Kb = Kr + (size_t)b * LL * CCH;
  for (int k0 = 0; k0 < CCH; k0 += 32) {
    __syncthreads();
#pragma unroll
    for (int s = 0; s < 8; ++s) {
      int u = t + 256 * s, r = u >> 5, cc = u & 31;
      Qs[r][cc] = (i0 + r < LL) ? Qb[(size_t)(i0 + r) * CCH + k0 + cc] : 0.f;
      Ks[r][cc] = (j0 + r < LL) ? Kb[(size_t)(j0 + r) * CCH + k0 + cc] : 0.f;
    }
    __syncthreads();
#pragma unroll
    for (int kk = 0; kk < 32; ++kk) {
      float qv[4], kv[4];
#pragma unroll
      for (int q = 0; q < 4; ++q) qv[q] = Qs[ti * 4 + q][kk];
#pragma unroll
      for (int j = 0; j < 4; ++j) kv[j] = Ks[tj * 4 + j][kk];
#pragma unroll
      for (int q = 0; q < 4; ++q)
#pragma unroll
        for (int j = 0; j < 4; ++j) acc[q][j] += qv[q] * kv[j];
    }
  }
#pragma unroll
  for (int q = 0; q < 4; ++q) {
    int i = i0 + ti * 4 + q;
    if (i >= LL) continue;
#pragma unroll
    for (int j = 0; j < 4; ++j) {
      int jj = j0 + tj * 4 + j;
      if (jj < LL) E[((size_t)b * LL + i) * LL + jj] = acc[q][j];
    }
  }
}

__global__ void softmax_k(float* __restrict__ E) {
  int row = blockIdx.x;                // 64*197
  int lane = threadIdx.x;              // 64
  float* Er = E + (size_t)row * LL;
  float v[4];
  float m = -3.4e38f;
#pragma unroll
  for (int q = 0; q < 4; ++q) {
    int j = lane + 64 * q;
    v[q] = (j < LL) ? Er[j] : -3.4e38f;
    m = fmaxf(m, v[q]);
  }
  for (int off = 32; off; off >>= 1) m = fmaxf(m, __shfl_down(m, off));
  m = __shfl(m, 0);
  float s = 0.f;
#pragma unroll
  for (int q = 0; q < 4; ++q) {
    int j = lane + 64 * q;
    v[q] = (j < LL) ? expf(v[q] - m) : 0.f;
    s += v[q];
  }
  for (int off = 32; off; off >>= 1) s += __shfl_down(s, off);
  s = __shfl(s, 0);
  float inv = 1.f / s;
#pragma unroll
  for (int q = 0; q < 4; ++q) {
    int j = lane + 64 * q;
    if (j < LL) Er[j] = v[q] * inv;
  }
}

// ---- fused AV + transpose: Y(b, c, i) = gamma*x + (a*[att@V] + b)^T.
__global__ void av_y(const float* __restrict__ att, const float* __restrict__ Ov,
                     const float* __restrict__ abn, const float* __restrict__ x,
                     const float* __restrict__ gamma, float* __restrict__ Y) {
  __shared__ float As[32][33];
  __shared__ float Vs[32][128];
  __shared__ float Ts[32][129];
  int i0 = blockIdx.x * 32, c0 = blockIdx.y * 128, b = blockIdx.z;
  int t = threadIdx.x, tc = t & 63, tq = t >> 6;
  const float* attb = att + (size_t)b * LL * LL;
  float acc[8][2] = {};
  for (int j0 = 0; j0 < LL; j0 += 32) {
    __syncthreads();
#pragma unroll
    for (int s = 0; s < 4; ++s) {
      int u = t + 256 * s, r = u >> 5, cc = u & 31;
      As[r][cc] = (i0 + r < LL && j0 + cc < LL) ? attb[(size_t)(i0 + r) * LL + j0 + cc] : 0.f;
    }
#pragma unroll
    for (int s = 0; s < 16; ++s) {
      int u = t + 256 * s, r = u >> 7, cc = u & 127;
      Vs[r][cc] = (j0 + r < LL) ? Ov[((size_t)b * LL + j0 + r) * CCH + c0 + cc] : 0.f;
    }
    __syncthreads();
#pragma unroll
    for (int jj = 0; jj < 32; ++jj) {
      f32x2 vv = *(const f32x2*)&Vs[jj][2 * tc];
#pragma unroll
      for (int q = 0; q < 8; ++q) {
        float a = As[tq * 8 + q][jj];
        acc[q][0] += a * vv[0];
        acc[q][1] += a * vv[1];
      }
    }
  }
  int c = c0 + 2 * tc;
  float a0 = abn[(2 * CCH + c) * 2],     b0 = abn[(2 * CCH + c) * 2 + 1];
  float a1 = abn[(2 * CCH + c + 1) * 2], b1 = abn[(2 * CCH + c + 1) * 2 + 1];
#pragma unroll
  for (int q = 0; q < 8; ++q) {
    int il = tq * 8 + q;
    Ts[il][2 * tc] = a0 * acc[q][0] + b0;
    Ts[il][2 * tc + 1] = a1 * acc[q][1] + b1;
  }
  __syncthreads();
  float g = gamma[0];
#pragma unroll
  for (int s = 0; s < 16; ++s) {
    int u = t + 256 * s, cc = u >> 5, il = u & 31;   // cc: 0..127, il: 0..31
    if (i0 + il < LL) {
      size_t idx = ((size_t)b * CCH + c0 + cc) * LL + i0 + il;
      Y[idx] = g * x[idx] + Ts[il][cc];
    }
  }
}

// ---- fused BN(Y) + apply
__global__ void bn_y_final(const float* __restrict__ Y, const float* __restrict__ ns,
                           const float* __restrict__ nb, float* __restrict__ out) {
  __shared__ float ych[12608];
  __shared__ float rs[256], rq[256];
  int c = blockIdx.x;
  int t = threadIdx.x;
  float s = 0.f, q = 0.f;
  for (int u = t; u < 12608; u += 256) {
    int b = u / LL, l = u - b * LL;
    float v = Y[((size_t)b * CCH + c) * LL + l];
    ych[u] = v;
    s += v; q += v * v;
  }
  rs[t] = s; rq[t] = q;
  __syncthreads();
  for (int off = 128; off; off >>= 1) {
    if (t < off) { rs[t] += rs[t + off]; rq[t] += rq[t + off]; }
    __syncthreads();
  }
  float mean = rs[0] / 12608.f, var = rq[0] / 12608.f - mean * mean;
  float a = ns[c] * rsqrtf(var + 1e-5f);
  float bb = nb[c] - mean * a;
  for (int u = t; u < 12608; u += 256) {
    int b = u / LL, l = u - b * LL;
    out[((size_t)b * CCH + c) * LL + l] = a * ych[u] + bb;
  }
}

extern "C" void kernel_launch(void* const* d_in, const int* in_sizes, int n_in,
                              void* d_out, int out_size, void* d_ws, size_t ws_size,
                              hipStream_t stream) {
  const float* x = (const float*)d_in[0];
  const float* Wq = (const float*)d_in[1];
  const float* Wk = (const float*)d_in[2];
  const float* Wv = (const float*)d_in[3];
  const float* bnq_s = (const float*)d_in[4];
  const float* bnq_b = (const float*)d_in[5];
  const float* bnk_s = (const float*)d_in[6];
  const float* bnk_b = (const float*)d_in[7];
  const float* bnv_s = (const float*)d_in[8];
  const float* bnv_b = (const float*)d_in[9];
  const float* gamma = (const float*)d_in[10];
  const float* freqs = (const float*)d_in[11];
  const float* norm_s = (const float*)d_in[12];
  const float* norm_b = (const float*)d_in[13];
  float* out = (float*)d_out;

  char* ws = (char*)d_ws;
  const size_t QRSZ  = 38731776;                 // 64*197*768*4
  const size_t PACK1 = 21233664;                 // per-proj Ahi+Alo bytes
  const size_t ZSZ   = 58705920;                 // 12740*2304*2

  const size_t OFS_PACK = 0;
  const size_t OFS_Z    = 3 * PACK1;
  const size_t OFS_ZLO  = OFS_Z + ZSZ;
  const size_t OFS_O    = OFS_ZLO + ZSZ;
  const size_t OFS_MISC = OFS_O + 2 * QRSZ;

  unsigned short* Apack = (unsigned short*)(ws + OFS_PACK);
  unsigned short* Zhi = (unsigned short*)(ws + OFS_Z);
  unsigned short* Zlo = (unsigned short*)(ws + OFS_ZLO);
  float* Oqk = (float*)(ws + OFS_O);
  float* bias3 = (float*)(ws + OFS_MISC);              // 27,648 B
  float* Ssum = (float*)(ws + OFS_MISC + 27648);       // 9,216 B
  float* Ssq  = (float*)(ws + OFS_MISC + 36864);       // 9,216 B
  float* abn  = (float*)(ws + OFS_MISC + 46080);       // 18,432 B
  // V lives in d_out until av_y consumes it; bn_y_final overwrites afterwards.
  float* Ov = out;
  // post-GEMM reuse of the Z region (Z dead after the GEMM launch):
  float* Qr = (float*)(ws + OFS_Z);                    // [0, QRSZ)
  float* Kr = (float*)(ws + OFS_Z + QRSZ);             // [QRSZ, 2*QRSZ)
  float* E  = (float*)(ws + OFS_Z + 2 * QRSZ);         // 9,935,104 B
  float* Y  = (float*)(ws + OFS_Z + QRSZ);             // after energy_k (Kr dead)

  zero_zpad<<<dim3((132 * KC + 255) / 256), 256, 0, stream>>>(Zhi, Zlo);
  z_kernel<<<dim3(24, 7, 64), 256, 0, stream>>>(x, Zhi, Zlo);
  pack_bias<<<dim3(2304), 256, 0, stream>>>(Wq, Wk, Wv, Apack, bias3, PACK1 / 2);
  conv_gemm3<<<dim3(450), 512, 0, stream>>>(Apack, Zhi, Zlo, bias3, Oqk, Ov);

  zero_f32<<<dim3(18), 256, 0, stream>>>(Ssum, 4608);   // Ssum+Ssq contiguous
  bn_stats<<<dim3(12, 32, 3), 256, 0, stream>>>(Oqk, Ov, Ssum, Ssq);
  bn_fin<<<dim3(9), 256, 0, stream>>>(Ssum, Ssq, bnq_s, bnq_b, bnk_s, bnk_b, bnv_s, bnv_b, abn);
  rope_pack<<<dim3((unsigned)((64ull * LL * 384 + 255) / 256)), 256, 0, stream>>>(Oqk, abn, freqs, Qr, Kr);
  energy_k<<<dim3(4, 4, 64), 256, 0, stream>>>(Qr, Kr, E);
  softmax_k<<<dim3(64 * LL), 64, 0, stream>>>(E);
  av_y<<<dim3(7, 6, 64), 256, 0, stream>>>(E, Ov, abn, x, gamma, Y);
  bn_y_final<<<dim3(CCH), 256, 0, stream>>>(Y, norm_s, norm_b, out);
}